// Round 14
// baseline (2610.087 us; speedup 1.0000x reference)
//
#include <hip/hip_runtime.h>
#include <cstdint>
#include <cstddef>

#define NPTS 8192
#define NB 8
#define NS 2048
#define KG 32
#define NROWS (NB*NS*KG)   // 524288
#define NREP 32            // stats atomic replication

// Distance with NO fma contraction: bitwise-identical to numpy f32
// ((dx*dx + dy*dy) + dz*dz).
__device__ __forceinline__ float dist2_exact(float ax, float ay, float az,
                                             float bx, float by, float bz)
{
#pragma clang fp contract(off)
  float dx = ax - bx;
  float dy = ay - by;
  float dz = az - bz;
  return dx * dx + dy * dy + dz * dz;
}

__device__ __forceinline__ unsigned mort3(unsigned v) {   // 3 bits -> bits 0,3,6
  return (v & 1u) | ((v & 2u) << 2) | ((v & 4u) << 4);
}

// ---- DPP u64 max step (VALU pipe; R12-proven: fps 1891->1683 us).
template<int CTRL>
__device__ __forceinline__ unsigned long long dpp_max_u64(unsigned long long v) {
  int hi = (int)(unsigned)(v >> 32), lo = (int)(unsigned)v;
  int h2 = __builtin_amdgcn_update_dpp(hi, hi, CTRL, 0xF, 0xF, false);
  int l2 = __builtin_amdgcn_update_dpp(lo, lo, CTRL, 0xF, 0xF, false);
  unsigned long long o = ((unsigned long long)(unsigned)h2 << 32) | (unsigned)l2;
  return (o > v) ? o : v;
}

// ======================== Morton counting sort (per batch) ========================
// [R7-proven] In-cell order nondeterministic (atomic cursors) — harmless:
// FPS selection is permutation-invariant (max dmin + min-ORIG-idx tiebreak).
__launch_bounds__(256)
__global__ void sort_kernel(const float* __restrict__ xyz,
                            float* __restrict__ sX, float* __restrict__ sY,
                            float* __restrict__ sZ, unsigned* __restrict__ sO)
{
  __shared__ unsigned hist[512];
  __shared__ unsigned startv[512];
  __shared__ unsigned short cellid[NPTS];   // 16 KB
  const int b = blockIdx.x, t = threadIdx.x;
  const float* base = xyz + (size_t)b * NPTS * 3;

  for (int q = t; q < 512; q += 256) hist[q] = 0u;
  __syncthreads();
  for (int q = t; q < NPTS; q += 256) {
    float x = base[3*q], y = base[3*q+1], z = base[3*q+2];
    int ix = (int)(x * 8.f); ix = ix < 0 ? 0 : (ix > 7 ? 7 : ix);
    int iy = (int)(y * 8.f); iy = iy < 0 ? 0 : (iy > 7 ? 7 : iy);
    int iz = (int)(z * 8.f); iz = iz < 0 ? 0 : (iz > 7 ? 7 : iz);
    unsigned m = mort3((unsigned)ix) | (mort3((unsigned)iy) << 1) | (mort3((unsigned)iz) << 2);
    cellid[q] = (unsigned short)m;
    atomicAdd(&hist[m], 1u);
  }
  __syncthreads();
  if (t == 0) {
    unsigned run = 0;
    for (int i = 0; i < 512; ++i) { unsigned h = hist[i]; startv[i] = run; run += h; }
  }
  __syncthreads();
  for (int q = t; q < NPTS; q += 256) {
    unsigned m = cellid[q];
    unsigned pos = atomicAdd(&startv[m], 1u);
    size_t o = (size_t)b * NPTS + pos;
    sX[o] = base[3*q]; sY[o] = base[3*q+1]; sZ[o] = base[3*q+2];
    sO[o] = (unsigned)q;
  }
}

// ======================== FPS (R12-proven best: wave-culled + DPP) ========================
// One block per batch, 512 threads x 16 pts. Each WAVE owns a contiguous
// 1024-pt Morton region (bbox in regs). Wave-uniform skip test (exact lower
// bound: skipped updates are bitwise no-ops; cached wave-max key stays
// valid). Active waves: lean phase-1, DPP u64 butterfly. One barrier
// (double-buffered partials), LDS coord broadcast, LDS-accumulated cents.
// Key = (dmin_bits<<32) | ~((orig<<13)|pos): max => argmax, first-ORIG tiebreak.
__launch_bounds__(512)
__global__ void fps_kernel(const float* __restrict__ sX, const float* __restrict__ sY,
                           const float* __restrict__ sZ, const unsigned* __restrict__ sO,
                           const float* __restrict__ xyz, float* __restrict__ cents)
{
  __shared__ float sx[NPTS], sy[NPTS], sz[NPTS];   // 96 KB (sorted order)
  __shared__ float scent[NS * 3];                  // 24 KB
  __shared__ unsigned long long spk[2][8];

  const int b = blockIdx.x;
  const int t = threadIdx.x;
  const int w = t >> 6, lane = t & 63;
  const size_t sb = (size_t)b * NPTS;

  float px[16], py[16], pz[16], dmin[16];
  unsigned lo[16];
#pragma unroll
  for (int j = 0; j < 16; ++j) {
    int i = w * 1024 + j * 64 + lane;          // wave-contiguous Morton region
    float x = sX[sb + i], y = sY[sb + i], z = sZ[sb + i];
    px[j] = x; py[j] = y; pz[j] = z;
    dmin[j] = 1e10f;
    lo[j] = ~((sO[sb + i] << 13) | (unsigned)i);
    sx[i] = x; sy[i] = y; sz[i] = z;
  }
  // wave bbox (region min/max per dim)
  float bxl = px[0], bxh = px[0], byl = py[0], byh = py[0], bzl = pz[0], bzh = pz[0];
#pragma unroll
  for (int j = 1; j < 16; ++j) {
    bxl = fminf(bxl, px[j]); bxh = fmaxf(bxh, px[j]);
    byl = fminf(byl, py[j]); byh = fmaxf(byh, py[j]);
    bzl = fminf(bzl, pz[j]); bzh = fmaxf(bzh, pz[j]);
  }
#pragma unroll
  for (int off = 1; off <= 32; off <<= 1) {
    bxl = fminf(bxl, __shfl_xor(bxl, off, 64)); bxh = fmaxf(bxh, __shfl_xor(bxh, off, 64));
    byl = fminf(byl, __shfl_xor(byl, off, 64)); byh = fmaxf(byh, __shfl_xor(byh, off, 64));
    bzl = fminf(bzl, __shfl_xor(bzl, off, 64)); bzh = fmaxf(bzh, __shfl_xor(bzh, off, 64));
  }

  // cached wave-max key; hi32 = 1e10 bits forces first iteration active
  unsigned long long bestc = ((unsigned long long)__float_as_uint(1e10f) << 32);

  const float* o0 = xyz + sb * 3;
  float cx = o0[0], cy = o0[1], cz = o0[2];
  if (t == 0) { scent[0] = cx; scent[1] = cy; scent[2] = cz; }
  __syncthreads();   // coords staged

  for (int it = 1; it < NS; ++it) {
    // ---- wave-uniform skip test
    float qx = cx - fminf(fmaxf(cx, bxl), bxh);
    float qy = cy - fminf(fmaxf(cy, byl), byh);
    float qz = cz - fminf(fmaxf(cz, bzl), bzh);
    float dbox2 = (qx*qx + qy*qy + qz*qz) * 0.999f;   // conservative lower bound
    float tmaxw = __uint_as_float((unsigned)(bestc >> 32));
    if (dbox2 < tmaxw) {
      // ---- phase 1: update dmin, track (bm, lob)
      float bm = -1.0f;
      unsigned lb = 0u;
#pragma unroll
      for (int j = 0; j < 16; ++j) {
        float d = dist2_exact(px[j], py[j], pz[j], cx, cy, cz);
        float m = fminf(dmin[j], d);
        dmin[j] = m;
        bool take = (m > bm);
        bm = take ? m : bm;
        lb = take ? lo[j] : lb;
      }
      unsigned long long best = ((unsigned long long)__float_as_uint(bm) << 32)
                              | (unsigned long long)lb;
      // ---- DPP butterfly (lane 63 accumulates wave max), uniform readlane
      best = dpp_max_u64<0x111>(best);   // row_shr:1
      best = dpp_max_u64<0x112>(best);   // row_shr:2
      best = dpp_max_u64<0x114>(best);   // row_shr:4
      best = dpp_max_u64<0x118>(best);   // row_shr:8
      best = dpp_max_u64<0x142>(best);   // row_bcast:15
      best = dpp_max_u64<0x143>(best);   // row_bcast:31
      unsigned bh = (unsigned)__builtin_amdgcn_readlane((int)(unsigned)(best >> 32), 63);
      unsigned bl = (unsigned)__builtin_amdgcn_readlane((int)(unsigned)best, 63);
      bestc = ((unsigned long long)bh << 32) | bl;
    }
    const int pb = it & 1;   // double-buffered partials -> single barrier/iter
    if (lane == 0) spk[pb][w] = bestc;
    __syncthreads();
    unsigned long long bb = spk[pb][0];
#pragma unroll
    for (int q = 1; q < 8; ++q) {
      unsigned long long oq = spk[pb][q];
      bb = (oq > bb) ? oq : bb;
    }
    const int win = (int)((~(unsigned)bb) & 8191u);   // sorted position
    cx = sx[win]; cy = sy[win]; cz = sz[win];         // same-address broadcast
    if (t == 0) { scent[3*it] = cx; scent[3*it+1] = cy; scent[3*it+2] = cz; }
  }
  __syncthreads();
  float* cb = cents + (size_t)b * NS * 3;
  for (int q = t; q < NS * 3; q += 512) cb[q] = scent[q];
}

// ======================== Ball query ========================
__launch_bounds__(256)
__global__ void ballq_kernel(const float* __restrict__ xyz,
                             const float* __restrict__ cents,
                             int* __restrict__ gidx)
{
  const int gid  = blockIdx.x * 256 + threadIdx.x;
  const int w    = gid >> 6;          // centroid id 0..16383
  const int lane = gid & 63;
  const int b    = w >> 11;
  const float* base = xyz + (size_t)b * NPTS * 3;
  const float cx = cents[3*w+0], cy = cents[3*w+1], cz = cents[3*w+2];
  const float R2 = (float)(0.2 * 0.2);
  int* out = gidx + (size_t)w * KG;

  int filled = 0, first = -1;
  for (int c = 0; c < NPTS/64; ++c) {
    int i = (c << 6) | lane;
    float d = dist2_exact(base[3*i+0], base[3*i+1], base[3*i+2], cx, cy, cz);
    bool inb = (d <= R2);
    unsigned long long mask = __ballot(inb);
    if (first < 0 && mask) first = (c << 6) + (__ffsll((long long)mask) - 1);
    int pre  = __popcll(mask & ((1ull << lane) - 1ull));
    int slot = filled + pre;
    if (inb && slot < KG) out[slot] = i;
    filled += __popcll(mask);
    if (filled >= KG) break;
  }
  if (filled < KG && lane < KG && lane >= filled) out[lane] = first;
}

// ======================== shuffle fold-reductions ========================
template<int H>
__device__ __forceinline__ void fold_sum_step(float* a, int lane) {
#pragma unroll
  for (int q = 0; q < H; ++q) {
    float keep = (lane & H) ? a[q + H] : a[q];
    float send = (lane & H) ? a[q] : a[q + H];
    a[q] = keep + __shfl_xor(send, H, 64);
  }
}

__device__ __forceinline__ float fold_sum16(float* a, int lane) {
  fold_sum_step<8>(a, lane);
  fold_sum_step<4>(a, lane);
  fold_sum_step<2>(a, lane);
  fold_sum_step<1>(a, lane);
  float v = a[0];
  v += __shfl_xor(v, 16, 64);
  v += __shfl_xor(v, 32, 64);
  return v;
}

template<int H>
__device__ __forceinline__ void fold_max_step(float* a, int lane) {
#pragma unroll
  for (int q = 0; q < H; ++q) {
    float keep = (lane & H) ? a[q + H] : a[q];
    float send = (lane & H) ? a[q] : a[q + H];
    a[q] = fmaxf(keep, __shfl_xor(send, H, 64));
  }
}

__device__ __forceinline__ float fold_max16(float* a, int lane) {
  fold_max_step<8>(a, lane);
  fold_max_step<4>(a, lane);
  fold_max_step<2>(a, lane);
  fold_max_step<1>(a, lane);
  float v = a[0];
  v = fmaxf(v, __shfl_xor(v, 16, 64));
  return v;
}

template<int H>
__device__ __forceinline__ void fold_min_step(float* a, int lane) {
#pragma unroll
  for (int q = 0; q < H; ++q) {
    float keep = (lane & H) ? a[q + H] : a[q];
    float send = (lane & H) ? a[q] : a[q + H];
    a[q] = fminf(keep, __shfl_xor(send, H, 64));
  }
}

__device__ __forceinline__ float fold_min16(float* a, int lane) {
  fold_min_step<8>(a, lane);
  fold_min_step<4>(a, lane);
  fold_min_step<2>(a, lane);
  fold_min_step<1>(a, lane);
  float v = a[0];
  v = fminf(v, __shfl_xor(v, 16, 64));
  return v;
}

// s1/s2 stats of 16 channels. Destroys y.
__device__ __forceinline__ void stats16(float* y, int lane, int o0,
                                        float* __restrict__ gs1,
                                        float* __restrict__ gs2)
{
  float sq[16];
#pragma unroll
  for (int q = 0; q < 16; ++q) sq[q] = y[q] * y[q];
  float s1 = fold_sum16(y, lane);
  float s2 = fold_sum16(sq, lane);
  if (lane < 16)       atomicAdd(&gs1[o0 + lane], s1);
  else if (lane < 32)  atomicAdd(&gs2[o0 + (lane & 15)], s2);
}

// k-group (32-row) max/min of y -> zmax/zmin[cs*128 + o0 + ch].
__device__ __forceinline__ void minmax16(const float* y, int lane, int o0, int cs,
                                         float* __restrict__ zmax,
                                         float* __restrict__ zmin)
{
  float ymx[16], ymn[16];
#pragma unroll
  for (int q = 0; q < 16; ++q) { ymx[q] = y[q]; ymn[q] = y[q]; }
  float mx = fold_max16(ymx, lane);
  float mn = fold_min16(ymn, lane);
  if (!(lane & 16)) {
    zmax[(size_t)cs * 128 + o0 + (lane & 15)] = mx;
    zmin[(size_t)cs * 128 + o0 + (lane & 15)] = mn;
  }
}

// ---- bf16 helpers (RNE pack; unpack by shift is free on packed u32)
__device__ __forceinline__ unsigned short f2b(float f) {
  unsigned b = __float_as_uint(f);
  return (unsigned short)((b + 0x7FFFu + ((b >> 16) & 1u)) >> 16);
}

// ======================== Tier A: bf16-cached chain (row-major packed) ========================
// actL layout: ROW-major [row][64ch] bf16 — each thread's row is 128 B
// contiguous: 8x b128 loads / 8x b64 stores instead of 64 strided 2B ops.
// Unpack of packed u32 is free (u<<16, u&0xffff0000). In-place reuse safe:
// each thread owns its whole row.
__launch_bounds__(256, 3)
__global__ void k1_kernel(const float* __restrict__ xyz, const float* __restrict__ feats,
                          const float* __restrict__ cents, const int* __restrict__ gidx,
                          const float* __restrict__ w0, const float* __restrict__ b0,
                          float* __restrict__ stats, unsigned int* __restrict__ actL)
{
  const int t = threadIdx.x, lane = t & 63;
  const int r = blockIdx.x * 256 + t;
  const int b = r >> 16, cs = r >> 5;
  const int i = gidx[r];
  const int rep = (blockIdx.x * 4 + (t >> 6)) & (NREP - 1);
  const float* pp = xyz + ((size_t)(b << 13) + i) * 3;
  const float* cc = cents + (size_t)cs * 3;
  const float* fb = feats + (((size_t)(b << 13) + i) << 6);

  float xin[67];
  xin[0] = pp[0] - cc[0]; xin[1] = pp[1] - cc[1]; xin[2] = pp[2] - cc[2];
  const float4* f4 = (const float4*)fb;
#pragma unroll
  for (int q = 0; q < 16; ++q) {
    float4 v = f4[q];
    xin[3+4*q+0] = v.x; xin[3+4*q+1] = v.y; xin[3+4*q+2] = v.z; xin[3+4*q+3] = v.w;
  }

  unsigned int* arow = actL + (size_t)r * 32;       // 32 u32 = 64 bf16
  for (int o0 = 0; o0 < 64; o0 += 16) {             // rolled: I$-resident body
    float y[16];
#pragma unroll
    for (int k = 0; k < 16; ++k) {
      float a = b0[o0 + k];
#pragma unroll
      for (int c = 0; c < 67; ++c)
        a = fmaf(w0[(o0 + k)*67 + c], xin[c], a);
      y[k] = a;
    }
#pragma unroll
    for (int k = 0; k < 16; k += 2)
      arow[(o0 + k) >> 1] = (unsigned)f2b(y[k]) | ((unsigned)f2b(y[k+1]) << 16);
    stats16(y, lane, o0, stats + (size_t)rep*64, stats + 2048 + (size_t)rep*64);
  }
}

__launch_bounds__(256, 3)
__global__ void k2_kernel(unsigned int* __restrict__ actL,
                          const float* __restrict__ w1, const float* __restrict__ b1,
                          const float* __restrict__ prm,
                          float* __restrict__ stats)
{
  const int t = threadIdx.x, lane = t & 63;
  const int r = blockIdx.x * 256 + t;
  const int rep = (blockIdx.x * 4 + (t >> 6)) & (NREP - 1);

  unsigned int* arow = actL + (size_t)r * 32;
  float x[64];
#pragma unroll
  for (int q = 0; q < 32; ++q) {
    unsigned u = arow[q];
    x[2*q]   = __uint_as_float(u << 16);
    x[2*q+1] = __uint_as_float(u & 0xFFFF0000u);
  }
#pragma unroll
  for (int c = 0; c < 64; ++c)
    x[c] = fmaxf(fmaf(prm[c], x[c], prm[64 + c]), 0.f);

  for (int o0 = 0; o0 < 64; o0 += 16) {
    float y[16];
#pragma unroll
    for (int k = 0; k < 16; ++k) {
      float a = b1[o0 + k];
#pragma unroll
      for (int c = 0; c < 64; ++c)
        a = fmaf(w1[(o0 + k)*64 + c], x[c], a);
      y[k] = a;
    }
#pragma unroll
    for (int k = 0; k < 16; k += 2)
      arow[(o0 + k) >> 1] = (unsigned)f2b(y[k]) | ((unsigned)f2b(y[k+1]) << 16);
    stats16(y, lane, o0, stats + 4096 + (size_t)rep*64, stats + 6144 + (size_t)rep*64);
  }
}

__launch_bounds__(256, 3)
__global__ void k3_kernel(const unsigned int* __restrict__ actL,
                          const float* __restrict__ w2, const float* __restrict__ b2,
                          const float* __restrict__ prm,
                          float* __restrict__ stats,
                          float* __restrict__ zmax, float* __restrict__ zmin)
{
  const int t = threadIdx.x, lane = t & 63;
  const int r = blockIdx.x * 256 + t;
  const int cs = r >> 5;
  const int rep = (blockIdx.x * 4 + (t >> 6)) & (NREP - 1);

  const unsigned int* arow = actL + (size_t)r * 32;
  float x[64];
#pragma unroll
  for (int q = 0; q < 32; ++q) {
    unsigned u = arow[q];
    x[2*q]   = __uint_as_float(u << 16);
    x[2*q+1] = __uint_as_float(u & 0xFFFF0000u);
  }
#pragma unroll
  for (int c = 0; c < 64; ++c)
    x[c] = fmaxf(fmaf(prm[128 + c], x[c], prm[192 + c]), 0.f);

  for (int o0 = 0; o0 < 128; o0 += 16) {
    float y[16];
#pragma unroll
    for (int k = 0; k < 16; ++k) {
      float a = b2[o0 + k];
#pragma unroll
      for (int c = 0; c < 64; ++c)
        a = fmaf(w2[(o0 + k)*64 + c], x[c], a);
      y[k] = a;
    }
    minmax16(y, lane, o0, cs, zmax, zmin);
    stats16(y, lane, o0, stats + 8192 + (size_t)rep*128, stats + 12288 + (size_t)rep*128);
  }
}

// out = relu(a*zsel + sh): max_k relu(a*z_k+sh) == relu(a*(a>=0?zmax:zmin)+sh)
__launch_bounds__(256)
__global__ void outfin_kernel(const float* __restrict__ zmax,
                              const float* __restrict__ zmin,
                              const float* __restrict__ prm,
                              float* __restrict__ outp)
{
  int i = blockIdx.x * 256 + threadIdx.x;      // 16384*128 total
  int ch = i & 127;
  float a = prm[256 + ch], sh = prm[384 + ch];
  float z = (a >= 0.f) ? zmax[i] : zmin[i];
  outp[i] = fmaxf(fmaf(a, z, sh), 0.f);
}

// ======================== Tier B/C: recompute chain ========================
template<int MODE>
__launch_bounds__(256, (MODE <= 2 ? 4 : 2))
__global__ void chain_kernel(const float* __restrict__ xyz,
                             const float* __restrict__ feats,
                             const float* __restrict__ cents,
                             const int* __restrict__ gidx,
                             const float* __restrict__ w0, const float* __restrict__ b0,
                             const float* __restrict__ w1, const float* __restrict__ b1,
                             const float* __restrict__ w2, const float* __restrict__ b2,
                             const float* __restrict__ prm,
                             float* __restrict__ stats,
                             float* __restrict__ outp,
                             float* __restrict__ zmax, float* __restrict__ zmin)
{
  const int t    = threadIdx.x;
  const int lane = t & 63;
  const int r    = blockIdx.x * 256 + t;
  const int b    = r >> 16;
  const int cs   = r >> 5;
  const int i    = gidx[r];
  const int rep  = (blockIdx.x * 4 + (t >> 6)) & (NREP - 1);

  const float* pp = xyz + ((size_t)(b << 13) + i) * 3;
  const float* cc = cents + (size_t)cs * 3;
  const float* fb = feats + (((size_t)(b << 13) + i) << 6);

  float acc[64];
  {
    float c0 = pp[0] - cc[0], c1 = pp[1] - cc[1], c2 = pp[2] - cc[2];
#pragma unroll
    for (int o = 0; o < 64; ++o)
      acc[o] = fmaf(w0[o*67+2], c2, fmaf(w0[o*67+1], c1, fmaf(w0[o*67+0], c0, b0[o])));
  }
  for (int c0 = 0; c0 < 64; c0 += 16) {
    float xc[16];
    const float4* f4 = (const float4*)(fb + c0);
    float4 v0 = f4[0], v1 = f4[1], v2 = f4[2], v3 = f4[3];
    xc[0]=v0.x; xc[1]=v0.y; xc[2]=v0.z; xc[3]=v0.w;
    xc[4]=v1.x; xc[5]=v1.y; xc[6]=v1.z; xc[7]=v1.w;
    xc[8]=v2.x; xc[9]=v2.y; xc[10]=v2.z; xc[11]=v2.w;
    xc[12]=v3.x; xc[13]=v3.y; xc[14]=v3.z; xc[15]=v3.w;
#pragma unroll
    for (int o = 0; o < 64; ++o) {
      float a = acc[o];
#pragma unroll
      for (int ci = 0; ci < 16; ++ci)
        a = fmaf(w0[o*67 + 3 + c0 + ci], xc[ci], a);
      acc[o] = a;
    }
  }

  if (MODE == 1) {
#pragma unroll
    for (int o0 = 0; o0 < 64; o0 += 16) {
      float y[16];
#pragma unroll
      for (int q = 0; q < 16; ++q) y[q] = acc[o0 + q];
      stats16(y, lane, o0, stats + (size_t)rep*64, stats + 2048 + (size_t)rep*64);
    }
    return;
  }

#pragma unroll
  for (int o = 0; o < 64; ++o)
    acc[o] = fmaxf(fmaf(prm[o], acc[o], prm[64 + o]), 0.f);

  if (MODE == 2) {
    for (int o0 = 0; o0 < 64; o0 += 16) {
      float y[16];
#pragma unroll
      for (int k = 0; k < 16; ++k) {
        float a = b1[o0 + k];
#pragma unroll
        for (int c = 0; c < 64; ++c)
          a = fmaf(w1[(o0 + k)*64 + c], acc[c], a);
        y[k] = a;
      }
      stats16(y, lane, o0, stats + 4096 + (size_t)rep*64, stats + 6144 + (size_t)rep*64);
    }
    return;
  }

  float y1[64];
#pragma unroll
  for (int o = 0; o < 64; ++o) {
    float a = b1[o];
#pragma unroll
    for (int c = 0; c < 64; ++c)
      a = fmaf(w1[o*64 + c], acc[c], a);
    y1[o] = a;
  }
#pragma unroll
  for (int o = 0; o < 64; ++o)
    y1[o] = fmaxf(fmaf(prm[128 + o], y1[o], prm[192 + o]), 0.f);

  if (MODE == 3 || MODE == 5) {
    for (int o0 = 0; o0 < 128; o0 += 16) {
      float y[16];
#pragma unroll
      for (int k = 0; k < 16; ++k) {
        float a = b2[o0 + k];
#pragma unroll
        for (int c = 0; c < 64; ++c)
          a = fmaf(w2[(o0 + k)*64 + c], y1[c], a);
        y[k] = a;
      }
      if (MODE == 5) minmax16(y, lane, o0, cs, zmax, zmin);
      stats16(y, lane, o0, stats + 8192 + (size_t)rep*128, stats + 12288 + (size_t)rep*128);
    }
    return;
  }

  // MODE 4 (tier C): norm2+relu+maxpool
  for (int o0 = 0; o0 < 128; o0 += 16) {
    float y[16];
#pragma unroll
    for (int k = 0; k < 16; ++k) {
      float a = b2[o0 + k];
#pragma unroll
      for (int c = 0; c < 64; ++c)
        a = fmaf(w2[(o0 + k)*64 + c], y1[c], a);
      y[k] = a;
    }
#pragma unroll
    for (int k = 0; k < 16; ++k)
      y[k] = fmaxf(fmaf(prm[256 + o0 + k], y[k], prm[384 + o0 + k]), 0.f);
    float m = fold_max16(y, lane);
    if (!(lane & 16))
      outp[(size_t)cs * 128 + o0 + (lane & 15)] = m;
  }
}

__global__ void finalize_kernel(const float* __restrict__ stats,
                                const float* __restrict__ g,
                                const float* __restrict__ beta,
                                float* __restrict__ pa, float* __restrict__ psh, int C)
{
  int c = threadIdx.x;
  if (c >= C) return;
  float s1 = 0.f, s2 = 0.f;
  for (int rr = 0; rr < NREP; ++rr) { s1 += stats[rr*C + c]; s2 += stats[NREP*C + rr*C + c]; }
  const float invn = 1.0f / (float)NROWS;
  float mean = s1 * invn;
  float var  = s2 * invn - mean * mean;
  float rs   = 1.0f / sqrtf(var + 1e-5f);
  float a    = g[c] * rs;
  pa[c]  = a;
  psh[c] = fmaf(-mean, a, beta[c]);
}

__global__ void zero_kernel(float* __restrict__ p, int n)
{
  int i = blockIdx.x * 256 + threadIdx.x;
  if (i < n) p[i] = 0.f;
}

// ======================== launch ========================
extern "C" void kernel_launch(void* const* d_in, const int* in_sizes, int n_in,
                              void* d_out, int out_size, void* d_ws, size_t ws_size,
                              hipStream_t stream)
{
  (void)in_sizes; (void)n_in; (void)out_size;
  const float* xyz   = (const float*)d_in[0];
  const float* feats = (const float*)d_in[1];
  const float* w0 = (const float*)d_in[2],  *b0 = (const float*)d_in[3];
  const float* g0 = (const float*)d_in[4],  *bt0 = (const float*)d_in[5];
  const float* w1 = (const float*)d_in[6],  *b1 = (const float*)d_in[7];
  const float* g1 = (const float*)d_in[8],  *bt1 = (const float*)d_in[9];
  const float* w2 = (const float*)d_in[10], *b2 = (const float*)d_in[11];
  const float* g2 = (const float*)d_in[12], *bt2 = (const float*)d_in[13];

  float* cents = (float*)d_out;                    // 8*2048*3
  float* outp  = cents + (size_t)NB * NS * 3;      // 8*2048*128

  // ws layout (R7-proven): gidx @0 (2 MiB) | stats @2MiB (64 KiB) | prm after |
  // sX/sY/sZ/sO @2MiB+512KiB (1 MiB) | zmax @4MiB | zmin @12MiB | actL @20MiB
  char* wsb = (char*)d_ws;
  int*   gidx  = (int*)wsb;
  float* stats = (float*)(wsb + (2ull << 20));
  float* prm   = stats + 16384;
  float* sX = (float*)(wsb + (2ull << 20) + (512u << 10));
  float* sY = sX + (size_t)NB * NPTS;
  float* sZ = sY + (size_t)NB * NPTS;
  unsigned* sO = (unsigned*)(sZ + (size_t)NB * NPTS);
  float* zmax  = (float*)(wsb + (4ull  << 20));
  float* zmin  = (float*)(wsb + (12ull << 20));
  unsigned int* actL = (unsigned int*)(wsb + (20ull << 20));   // 64 MiB
  const size_t need_A = (20ull << 20) + (size_t)NROWS * 64 * 2;
  const size_t need_B = (20ull << 20);

  zero_kernel<<<64, 256, 0, stream>>>(stats, 16384);
  sort_kernel<<<NB, 256, 0, stream>>>(xyz, sX, sY, sZ, sO);
  fps_kernel<<<NB, 512, 0, stream>>>(sX, sY, sZ, sO, xyz, cents);
  ballq_kernel<<<(NB*NS*64)/256, 256, 0, stream>>>(xyz, cents, gidx);

  if (ws_size >= need_A) {
    k1_kernel<<<NROWS/256, 256, 0, stream>>>(xyz, feats, cents, gidx, w0, b0, stats, actL);
    finalize_kernel<<<1, 128, 0, stream>>>(stats + 0, g0, bt0, prm + 0, prm + 64, 64);
    k2_kernel<<<NROWS/256, 256, 0, stream>>>(actL, w1, b1, prm, stats);
    finalize_kernel<<<1, 128, 0, stream>>>(stats + 4096, g1, bt1, prm + 128, prm + 192, 64);
    k3_kernel<<<NROWS/256, 256, 0, stream>>>(actL, w2, b2, prm, stats, zmax, zmin);
    finalize_kernel<<<1, 128, 0, stream>>>(stats + 8192, g2, bt2, prm + 256, prm + 384, 128);
    outfin_kernel<<<(16384*128)/256, 256, 0, stream>>>(zmax, zmin, prm, outp);
  } else if (ws_size >= need_B) {
    chain_kernel<1><<<NROWS/256, 256, 0, stream>>>(xyz, feats, cents, gidx,
        w0, b0, w1, b1, w2, b2, prm, stats, outp, zmax, zmin);
    finalize_kernel<<<1, 128, 0, stream>>>(stats + 0, g0, bt0, prm + 0, prm + 64, 64);
    chain_kernel<2><<<NROWS/256, 256, 0, stream>>>(xyz, feats, cents, gidx,
        w0, b0, w1, b1, w2, b2, prm, stats, outp, zmax, zmin);
    finalize_kernel<<<1, 128, 0, stream>>>(stats + 4096, g1, bt1, prm + 128, prm + 192, 64);
    chain_kernel<5><<<NROWS/256, 256, 0, stream>>>(xyz, feats, cents, gidx,
        w0, b0, w1, b1, w2, b2, prm, stats, outp, zmax, zmin);
    finalize_kernel<<<1, 128, 0, stream>>>(stats + 8192, g2, bt2, prm + 256, prm + 384, 128);
    outfin_kernel<<<(16384*128)/256, 256, 0, stream>>>(zmax, zmin, prm, outp);
  } else {
    chain_kernel<1><<<NROWS/256, 256, 0, stream>>>(xyz, feats, cents, gidx,
        w0, b0, w1, b1, w2, b2, prm, stats, outp, zmax, zmin);
    finalize_kernel<<<1, 128, 0, stream>>>(stats + 0, g0, bt0, prm + 0, prm + 64, 64);
    chain_kernel<2><<<NROWS/256, 256, 0, stream>>>(xyz, feats, cents, gidx,
        w0, b0, w1, b1, w2, b2, prm, stats, outp, zmax, zmin);
    finalize_kernel<<<1, 128, 0, stream>>>(stats + 4096, g1, bt1, prm + 128, prm + 192, 64);
    chain_kernel<3><<<NROWS/256, 256, 0, stream>>>(xyz, feats, cents, gidx,
        w0, b0, w1, b1, w2, b2, prm, stats, outp, zmax, zmin);
    finalize_kernel<<<1, 128, 0, stream>>>(stats + 8192, g2, bt2, prm + 256, prm + 384, 128);
    chain_kernel<4><<<NROWS/256, 256, 0, stream>>>(xyz, feats, cents, gidx,
        w0, b0, w1, b1, w2, b2, prm, stats, outp, zmax, zmin);
  }
}

// Round 15
// 2314.445 us; speedup vs baseline: 1.1277x; 1.1277x over previous
//
#include <hip/hip_runtime.h>
#include <cstdint>
#include <cstddef>

#define NPTS 8192
#define NB 8
#define NS 2048
#define KG 32
#define NROWS (NB*NS*KG)   // 524288
#define NREP 32            // stats atomic replication

// Distance with NO fma contraction: bitwise-identical to numpy f32
// ((dx*dx + dy*dy) + dz*dz).
__device__ __forceinline__ float dist2_exact(float ax, float ay, float az,
                                             float bx, float by, float bz)
{
#pragma clang fp contract(off)
  float dx = ax - bx;
  float dy = ay - by;
  float dz = az - bz;
  return dx * dx + dy * dy + dz * dz;
}

__device__ __forceinline__ unsigned mort3(unsigned v) {   // 3 bits -> bits 0,3,6
  return (v & 1u) | ((v & 2u) << 2) | ((v & 4u) << 4);
}

// ---- DPP u64 max step (VALU pipe; R12-proven: fps 1891->1683 us).
template<int CTRL>
__device__ __forceinline__ unsigned long long dpp_max_u64(unsigned long long v) {
  int hi = (int)(unsigned)(v >> 32), lo = (int)(unsigned)v;
  int h2 = __builtin_amdgcn_update_dpp(hi, hi, CTRL, 0xF, 0xF, false);
  int l2 = __builtin_amdgcn_update_dpp(lo, lo, CTRL, 0xF, 0xF, false);
  unsigned long long o = ((unsigned long long)(unsigned)h2 << 32) | (unsigned)l2;
  return (o > v) ? o : v;
}

// ======================== Morton counting sort (per batch) ========================
// [R7-proven] In-cell order nondeterministic (atomic cursors) — harmless:
// FPS selection is permutation-invariant (max dmin + min-ORIG-idx tiebreak).
__launch_bounds__(256)
__global__ void sort_kernel(const float* __restrict__ xyz,
                            float* __restrict__ sX, float* __restrict__ sY,
                            float* __restrict__ sZ, unsigned* __restrict__ sO)
{
  __shared__ unsigned hist[512];
  __shared__ unsigned startv[512];
  __shared__ unsigned short cellid[NPTS];   // 16 KB
  const int b = blockIdx.x, t = threadIdx.x;
  const float* base = xyz + (size_t)b * NPTS * 3;

  for (int q = t; q < 512; q += 256) hist[q] = 0u;
  __syncthreads();
  for (int q = t; q < NPTS; q += 256) {
    float x = base[3*q], y = base[3*q+1], z = base[3*q+2];
    int ix = (int)(x * 8.f); ix = ix < 0 ? 0 : (ix > 7 ? 7 : ix);
    int iy = (int)(y * 8.f); iy = iy < 0 ? 0 : (iy > 7 ? 7 : iy);
    int iz = (int)(z * 8.f); iz = iz < 0 ? 0 : (iz > 7 ? 7 : iz);
    unsigned m = mort3((unsigned)ix) | (mort3((unsigned)iy) << 1) | (mort3((unsigned)iz) << 2);
    cellid[q] = (unsigned short)m;
    atomicAdd(&hist[m], 1u);
  }
  __syncthreads();
  if (t == 0) {
    unsigned run = 0;
    for (int i = 0; i < 512; ++i) { unsigned h = hist[i]; startv[i] = run; run += h; }
  }
  __syncthreads();
  for (int q = t; q < NPTS; q += 256) {
    unsigned m = cellid[q];
    unsigned pos = atomicAdd(&startv[m], 1u);
    size_t o = (size_t)b * NPTS + pos;
    sX[o] = base[3*q]; sY[o] = base[3*q+1]; sZ[o] = base[3*q+2];
    sO[o] = (unsigned)q;
  }
}

// ======================== FPS (R12-proven best: wave-culled + DPP) ========================
// One block per batch, 512 threads x 16 pts. Each WAVE owns a contiguous
// 1024-pt Morton region (bbox in regs). Wave-uniform skip test (exact lower
// bound: skipped updates are bitwise no-ops; cached wave-max key stays
// valid). Active waves: lean phase-1, DPP u64 butterfly. One barrier
// (double-buffered partials), LDS coord broadcast, LDS-accumulated cents.
// Key = (dmin_bits<<32) | ~((orig<<13)|pos): max => argmax, first-ORIG tiebreak.
__launch_bounds__(512)
__global__ void fps_kernel(const float* __restrict__ sX, const float* __restrict__ sY,
                           const float* __restrict__ sZ, const unsigned* __restrict__ sO,
                           const float* __restrict__ xyz, float* __restrict__ cents)
{
  __shared__ float sx[NPTS], sy[NPTS], sz[NPTS];   // 96 KB (sorted order)
  __shared__ float scent[NS * 3];                  // 24 KB
  __shared__ unsigned long long spk[2][8];

  const int b = blockIdx.x;
  const int t = threadIdx.x;
  const int w = t >> 6, lane = t & 63;
  const size_t sb = (size_t)b * NPTS;

  float px[16], py[16], pz[16], dmin[16];
  unsigned lo[16];
#pragma unroll
  for (int j = 0; j < 16; ++j) {
    int i = w * 1024 + j * 64 + lane;          // wave-contiguous Morton region
    float x = sX[sb + i], y = sY[sb + i], z = sZ[sb + i];
    px[j] = x; py[j] = y; pz[j] = z;
    dmin[j] = 1e10f;
    lo[j] = ~((sO[sb + i] << 13) | (unsigned)i);
    sx[i] = x; sy[i] = y; sz[i] = z;
  }
  // wave bbox (region min/max per dim)
  float bxl = px[0], bxh = px[0], byl = py[0], byh = py[0], bzl = pz[0], bzh = pz[0];
#pragma unroll
  for (int j = 1; j < 16; ++j) {
    bxl = fminf(bxl, px[j]); bxh = fmaxf(bxh, px[j]);
    byl = fminf(byl, py[j]); byh = fmaxf(byh, py[j]);
    bzl = fminf(bzl, pz[j]); bzh = fmaxf(bzh, pz[j]);
  }
#pragma unroll
  for (int off = 1; off <= 32; off <<= 1) {
    bxl = fminf(bxl, __shfl_xor(bxl, off, 64)); bxh = fmaxf(bxh, __shfl_xor(bxh, off, 64));
    byl = fminf(byl, __shfl_xor(byl, off, 64)); byh = fmaxf(byh, __shfl_xor(byh, off, 64));
    bzl = fminf(bzl, __shfl_xor(bzl, off, 64)); bzh = fmaxf(bzh, __shfl_xor(bzh, off, 64));
  }

  // cached wave-max key; hi32 = 1e10 bits forces first iteration active
  unsigned long long bestc = ((unsigned long long)__float_as_uint(1e10f) << 32);

  const float* o0 = xyz + sb * 3;
  float cx = o0[0], cy = o0[1], cz = o0[2];
  if (t == 0) { scent[0] = cx; scent[1] = cy; scent[2] = cz; }
  __syncthreads();   // coords staged

  for (int it = 1; it < NS; ++it) {
    // ---- wave-uniform skip test
    float qx = cx - fminf(fmaxf(cx, bxl), bxh);
    float qy = cy - fminf(fmaxf(cy, byl), byh);
    float qz = cz - fminf(fmaxf(cz, bzl), bzh);
    float dbox2 = (qx*qx + qy*qy + qz*qz) * 0.999f;   // conservative lower bound
    float tmaxw = __uint_as_float((unsigned)(bestc >> 32));
    if (dbox2 < tmaxw) {
      // ---- phase 1: update dmin, track (bm, lob)
      float bm = -1.0f;
      unsigned lb = 0u;
#pragma unroll
      for (int j = 0; j < 16; ++j) {
        float d = dist2_exact(px[j], py[j], pz[j], cx, cy, cz);
        float m = fminf(dmin[j], d);
        dmin[j] = m;
        bool take = (m > bm);
        bm = take ? m : bm;
        lb = take ? lo[j] : lb;
      }
      unsigned long long best = ((unsigned long long)__float_as_uint(bm) << 32)
                              | (unsigned long long)lb;
      // ---- DPP butterfly (lane 63 accumulates wave max), uniform readlane
      best = dpp_max_u64<0x111>(best);   // row_shr:1
      best = dpp_max_u64<0x112>(best);   // row_shr:2
      best = dpp_max_u64<0x114>(best);   // row_shr:4
      best = dpp_max_u64<0x118>(best);   // row_shr:8
      best = dpp_max_u64<0x142>(best);   // row_bcast:15
      best = dpp_max_u64<0x143>(best);   // row_bcast:31
      unsigned bh = (unsigned)__builtin_amdgcn_readlane((int)(unsigned)(best >> 32), 63);
      unsigned bl = (unsigned)__builtin_amdgcn_readlane((int)(unsigned)best, 63);
      bestc = ((unsigned long long)bh << 32) | bl;
    }
    const int pb = it & 1;   // double-buffered partials -> single barrier/iter
    if (lane == 0) spk[pb][w] = bestc;
    __syncthreads();
    unsigned long long bb = spk[pb][0];
#pragma unroll
    for (int q = 1; q < 8; ++q) {
      unsigned long long oq = spk[pb][q];
      bb = (oq > bb) ? oq : bb;
    }
    const int win = (int)((~(unsigned)bb) & 8191u);   // sorted position
    cx = sx[win]; cy = sy[win]; cz = sz[win];         // same-address broadcast
    if (t == 0) { scent[3*it] = cx; scent[3*it+1] = cy; scent[3*it+2] = cz; }
  }
  __syncthreads();
  float* cb = cents + (size_t)b * NS * 3;
  for (int q = t; q < NS * 3; q += 512) cb[q] = scent[q];
}

// ======================== Ball query ========================
__launch_bounds__(256)
__global__ void ballq_kernel(const float* __restrict__ xyz,
                             const float* __restrict__ cents,
                             int* __restrict__ gidx)
{
  const int gid  = blockIdx.x * 256 + threadIdx.x;
  const int w    = gid >> 6;          // centroid id 0..16383
  const int lane = gid & 63;
  const int b    = w >> 11;
  const float* base = xyz + (size_t)b * NPTS * 3;
  const float cx = cents[3*w+0], cy = cents[3*w+1], cz = cents[3*w+2];
  const float R2 = (float)(0.2 * 0.2);
  int* out = gidx + (size_t)w * KG;

  int filled = 0, first = -1;
  for (int c = 0; c < NPTS/64; ++c) {
    int i = (c << 6) | lane;
    float d = dist2_exact(base[3*i+0], base[3*i+1], base[3*i+2], cx, cy, cz);
    bool inb = (d <= R2);
    unsigned long long mask = __ballot(inb);
    if (first < 0 && mask) first = (c << 6) + (__ffsll((long long)mask) - 1);
    int pre  = __popcll(mask & ((1ull << lane) - 1ull));
    int slot = filled + pre;
    if (inb && slot < KG) out[slot] = i;
    filled += __popcll(mask);
    if (filled >= KG) break;
  }
  if (filled < KG && lane < KG && lane >= filled) out[lane] = first;
}

// ======================== shuffle fold-reductions ========================
template<int H>
__device__ __forceinline__ void fold_sum_step(float* a, int lane) {
#pragma unroll
  for (int q = 0; q < H; ++q) {
    float keep = (lane & H) ? a[q + H] : a[q];
    float send = (lane & H) ? a[q] : a[q + H];
    a[q] = keep + __shfl_xor(send, H, 64);
  }
}

__device__ __forceinline__ float fold_sum16(float* a, int lane) {
  fold_sum_step<8>(a, lane);
  fold_sum_step<4>(a, lane);
  fold_sum_step<2>(a, lane);
  fold_sum_step<1>(a, lane);
  float v = a[0];
  v += __shfl_xor(v, 16, 64);
  v += __shfl_xor(v, 32, 64);
  return v;
}

template<int H>
__device__ __forceinline__ void fold_max_step(float* a, int lane) {
#pragma unroll
  for (int q = 0; q < H; ++q) {
    float keep = (lane & H) ? a[q + H] : a[q];
    float send = (lane & H) ? a[q] : a[q + H];
    a[q] = fmaxf(keep, __shfl_xor(send, H, 64));
  }
}

__device__ __forceinline__ float fold_max16(float* a, int lane) {
  fold_max_step<8>(a, lane);
  fold_max_step<4>(a, lane);
  fold_max_step<2>(a, lane);
  fold_max_step<1>(a, lane);
  float v = a[0];
  v = fmaxf(v, __shfl_xor(v, 16, 64));
  return v;
}

template<int H>
__device__ __forceinline__ void fold_min_step(float* a, int lane) {
#pragma unroll
  for (int q = 0; q < H; ++q) {
    float keep = (lane & H) ? a[q + H] : a[q];
    float send = (lane & H) ? a[q] : a[q + H];
    a[q] = fminf(keep, __shfl_xor(send, H, 64));
  }
}

__device__ __forceinline__ float fold_min16(float* a, int lane) {
  fold_min_step<8>(a, lane);
  fold_min_step<4>(a, lane);
  fold_min_step<2>(a, lane);
  fold_min_step<1>(a, lane);
  float v = a[0];
  v = fminf(v, __shfl_xor(v, 16, 64));
  return v;
}

// s1/s2 stats of 16 channels. Destroys y.
__device__ __forceinline__ void stats16(float* y, int lane, int o0,
                                        float* __restrict__ gs1,
                                        float* __restrict__ gs2)
{
  float sq[16];
#pragma unroll
  for (int q = 0; q < 16; ++q) sq[q] = y[q] * y[q];
  float s1 = fold_sum16(y, lane);
  float s2 = fold_sum16(sq, lane);
  if (lane < 16)       atomicAdd(&gs1[o0 + lane], s1);
  else if (lane < 32)  atomicAdd(&gs2[o0 + (lane & 15)], s2);
}

// k-group (32-row) max/min of y -> zmax/zmin[cs*128 + o0 + ch].
__device__ __forceinline__ void minmax16(const float* y, int lane, int o0, int cs,
                                         float* __restrict__ zmax,
                                         float* __restrict__ zmin)
{
  float ymx[16], ymn[16];
#pragma unroll
  for (int q = 0; q < 16; ++q) { ymx[q] = y[q]; ymn[q] = y[q]; }
  float mx = fold_max16(ymx, lane);
  float mn = fold_min16(ymn, lane);
  if (!(lane & 16)) {
    zmax[(size_t)cs * 128 + o0 + (lane & 15)] = mx;
    zmin[(size_t)cs * 128 + o0 + (lane & 15)] = mn;
  }
}

// ---- bf16 helpers (RNE pack, shift unpack)
__device__ __forceinline__ unsigned short f2b(float f) {
  unsigned b = __float_as_uint(f);
  return (unsigned short)((b + 0x7FFFu + ((b >> 16) & 1u)) >> 16);
}
__device__ __forceinline__ float b2f(unsigned short h) {
  return __uint_as_float(((unsigned)h) << 16);
}

// ======================== Tier A: bf16-cached chain (R9/R12-proven form) ========================
// actL: CHANNEL-major [64][NROWS] bf16 — consecutive lanes access consecutive
// 2B elements: perfectly coalesced (1 segment/instr). R14's row-major b128
// variant regressed ~280us: per-lane 128B stride => 64 scattered cache lines
// per VMEM instr (16B used of 64B) — 4x the L1/TA transactions.
__launch_bounds__(256, 3)
__global__ void k1_kernel(const float* __restrict__ xyz, const float* __restrict__ feats,
                          const float* __restrict__ cents, const int* __restrict__ gidx,
                          const float* __restrict__ w0, const float* __restrict__ b0,
                          float* __restrict__ stats, unsigned short* __restrict__ actL)
{
  const int t = threadIdx.x, lane = t & 63;
  const int r = blockIdx.x * 256 + t;
  const int b = r >> 16, cs = r >> 5;
  const int i = gidx[r];
  const int rep = (blockIdx.x * 4 + (t >> 6)) & (NREP - 1);
  const float* pp = xyz + ((size_t)(b << 13) + i) * 3;
  const float* cc = cents + (size_t)cs * 3;
  const float* fb = feats + (((size_t)(b << 13) + i) << 6);

  float xin[67];
  xin[0] = pp[0] - cc[0]; xin[1] = pp[1] - cc[1]; xin[2] = pp[2] - cc[2];
  const float4* f4 = (const float4*)fb;
#pragma unroll
  for (int q = 0; q < 16; ++q) {
    float4 v = f4[q];
    xin[3+4*q+0] = v.x; xin[3+4*q+1] = v.y; xin[3+4*q+2] = v.z; xin[3+4*q+3] = v.w;
  }

  for (int o0 = 0; o0 < 64; o0 += 16) {     // rolled: I$-resident body
    float y[16];
#pragma unroll
    for (int k = 0; k < 16; ++k) {
      float a = b0[o0 + k];
#pragma unroll
      for (int c = 0; c < 67; ++c)
        a = fmaf(w0[(o0 + k)*67 + c], xin[c], a);
      y[k] = a;
    }
#pragma unroll
    for (int k = 0; k < 16; ++k)
      actL[(size_t)(o0 + k) * NROWS + r] = f2b(y[k]);
    stats16(y, lane, o0, stats + (size_t)rep*64, stats + 2048 + (size_t)rep*64);
  }
}

__launch_bounds__(256, 3)
__global__ void k2_kernel(unsigned short* __restrict__ actL,
                          const float* __restrict__ w1, const float* __restrict__ b1,
                          const float* __restrict__ prm,
                          float* __restrict__ stats)
{
  const int t = threadIdx.x, lane = t & 63;
  const int r = blockIdx.x * 256 + t;
  const int rep = (blockIdx.x * 4 + (t >> 6)) & (NREP - 1);

  float x[64];
#pragma unroll
  for (int c = 0; c < 64; ++c)
    x[c] = b2f(actL[(size_t)c * NROWS + r]);
#pragma unroll
  for (int c = 0; c < 64; ++c)
    x[c] = fmaxf(fmaf(prm[c], x[c], prm[64 + c]), 0.f);

  for (int o0 = 0; o0 < 64; o0 += 16) {
    float y[16];
#pragma unroll
    for (int k = 0; k < 16; ++k) {
      float a = b1[o0 + k];
#pragma unroll
      for (int c = 0; c < 64; ++c)
        a = fmaf(w1[(o0 + k)*64 + c], x[c], a);
      y[k] = a;
    }
#pragma unroll
    for (int k = 0; k < 16; ++k)
      actL[(size_t)(o0 + k) * NROWS + r] = f2b(y[k]);   // in-place: col r only
    stats16(y, lane, o0, stats + 4096 + (size_t)rep*64, stats + 6144 + (size_t)rep*64);
  }
}

__launch_bounds__(256, 3)
__global__ void k3_kernel(const unsigned short* __restrict__ actL,
                          const float* __restrict__ w2, const float* __restrict__ b2,
                          const float* __restrict__ prm,
                          float* __restrict__ stats,
                          float* __restrict__ zmax, float* __restrict__ zmin)
{
  const int t = threadIdx.x, lane = t & 63;
  const int r = blockIdx.x * 256 + t;
  const int cs = r >> 5;
  const int rep = (blockIdx.x * 4 + (t >> 6)) & (NREP - 1);

  float x[64];
#pragma unroll
  for (int c = 0; c < 64; ++c)
    x[c] = b2f(actL[(size_t)c * NROWS + r]);
#pragma unroll
  for (int c = 0; c < 64; ++c)
    x[c] = fmaxf(fmaf(prm[128 + c], x[c], prm[192 + c]), 0.f);

  for (int o0 = 0; o0 < 128; o0 += 16) {
    float y[16];
#pragma unroll
    for (int k = 0; k < 16; ++k) {
      float a = b2[o0 + k];
#pragma unroll
      for (int c = 0; c < 64; ++c)
        a = fmaf(w2[(o0 + k)*64 + c], x[c], a);
      y[k] = a;
    }
    minmax16(y, lane, o0, cs, zmax, zmin);
    stats16(y, lane, o0, stats + 8192 + (size_t)rep*128, stats + 12288 + (size_t)rep*128);
  }
}

// out = relu(a*zsel + sh): max_k relu(a*z_k+sh) == relu(a*(a>=0?zmax:zmin)+sh)
__launch_bounds__(256)
__global__ void outfin_kernel(const float* __restrict__ zmax,
                              const float* __restrict__ zmin,
                              const float* __restrict__ prm,
                              float* __restrict__ outp)
{
  int i = blockIdx.x * 256 + threadIdx.x;      // 16384*128 total
  int ch = i & 127;
  float a = prm[256 + ch], sh = prm[384 + ch];
  float z = (a >= 0.f) ? zmax[i] : zmin[i];
  outp[i] = fmaxf(fmaf(a, z, sh), 0.f);
}

// ======================== Tier B/C: recompute chain ========================
template<int MODE>
__launch_bounds__(256, (MODE <= 2 ? 4 : 2))
__global__ void chain_kernel(const float* __restrict__ xyz,
                             const float* __restrict__ feats,
                             const float* __restrict__ cents,
                             const int* __restrict__ gidx,
                             const float* __restrict__ w0, const float* __restrict__ b0,
                             const float* __restrict__ w1, const float* __restrict__ b1,
                             const float* __restrict__ w2, const float* __restrict__ b2,
                             const float* __restrict__ prm,
                             float* __restrict__ stats,
                             float* __restrict__ outp,
                             float* __restrict__ zmax, float* __restrict__ zmin)
{
  const int t    = threadIdx.x;
  const int lane = t & 63;
  const int r    = blockIdx.x * 256 + t;
  const int b    = r >> 16;
  const int cs   = r >> 5;
  const int i    = gidx[r];
  const int rep  = (blockIdx.x * 4 + (t >> 6)) & (NREP - 1);

  const float* pp = xyz + ((size_t)(b << 13) + i) * 3;
  const float* cc = cents + (size_t)cs * 3;
  const float* fb = feats + (((size_t)(b << 13) + i) << 6);

  float acc[64];
  {
    float c0 = pp[0] - cc[0], c1 = pp[1] - cc[1], c2 = pp[2] - cc[2];
#pragma unroll
    for (int o = 0; o < 64; ++o)
      acc[o] = fmaf(w0[o*67+2], c2, fmaf(w0[o*67+1], c1, fmaf(w0[o*67+0], c0, b0[o])));
  }
  for (int c0 = 0; c0 < 64; c0 += 16) {
    float xc[16];
    const float4* f4 = (const float4*)(fb + c0);
    float4 v0 = f4[0], v1 = f4[1], v2 = f4[2], v3 = f4[3];
    xc[0]=v0.x; xc[1]=v0.y; xc[2]=v0.z; xc[3]=v0.w;
    xc[4]=v1.x; xc[5]=v1.y; xc[6]=v1.z; xc[7]=v1.w;
    xc[8]=v2.x; xc[9]=v2.y; xc[10]=v2.z; xc[11]=v2.w;
    xc[12]=v3.x; xc[13]=v3.y; xc[14]=v3.z; xc[15]=v3.w;
#pragma unroll
    for (int o = 0; o < 64; ++o) {
      float a = acc[o];
#pragma unroll
      for (int ci = 0; ci < 16; ++ci)
        a = fmaf(w0[o*67 + 3 + c0 + ci], xc[ci], a);
      acc[o] = a;
    }
  }

  if (MODE == 1) {
#pragma unroll
    for (int o0 = 0; o0 < 64; o0 += 16) {
      float y[16];
#pragma unroll
      for (int q = 0; q < 16; ++q) y[q] = acc[o0 + q];
      stats16(y, lane, o0, stats + (size_t)rep*64, stats + 2048 + (size_t)rep*64);
    }
    return;
  }

#pragma unroll
  for (int o = 0; o < 64; ++o)
    acc[o] = fmaxf(fmaf(prm[o], acc[o], prm[64 + o]), 0.f);

  if (MODE == 2) {
    for (int o0 = 0; o0 < 64; o0 += 16) {
      float y[16];
#pragma unroll
      for (int k = 0; k < 16; ++k) {
        float a = b1[o0 + k];
#pragma unroll
        for (int c = 0; c < 64; ++c)
          a = fmaf(w1[(o0 + k)*64 + c], acc[c], a);
        y[k] = a;
      }
      stats16(y, lane, o0, stats + 4096 + (size_t)rep*64, stats + 6144 + (size_t)rep*64);
    }
    return;
  }

  float y1[64];
#pragma unroll
  for (int o = 0; o < 64; ++o) {
    float a = b1[o];
#pragma unroll
    for (int c = 0; c < 64; ++c)
      a = fmaf(w1[o*64 + c], acc[c], a);
    y1[o] = a;
  }
#pragma unroll
  for (int o = 0; o < 64; ++o)
    y1[o] = fmaxf(fmaf(prm[128 + o], y1[o], prm[192 + o]), 0.f);

  if (MODE == 3 || MODE == 5) {
    for (int o0 = 0; o0 < 128; o0 += 16) {
      float y[16];
#pragma unroll
      for (int k = 0; k < 16; ++k) {
        float a = b2[o0 + k];
#pragma unroll
        for (int c = 0; c < 64; ++c)
          a = fmaf(w2[(o0 + k)*64 + c], y1[c], a);
        y[k] = a;
      }
      if (MODE == 5) minmax16(y, lane, o0, cs, zmax, zmin);
      stats16(y, lane, o0, stats + 8192 + (size_t)rep*128, stats + 12288 + (size_t)rep*128);
    }
    return;
  }

  // MODE 4 (tier C): norm2+relu+maxpool
  for (int o0 = 0; o0 < 128; o0 += 16) {
    float y[16];
#pragma unroll
    for (int k = 0; k < 16; ++k) {
      float a = b2[o0 + k];
#pragma unroll
      for (int c = 0; c < 64; ++c)
        a = fmaf(w2[(o0 + k)*64 + c], y1[c], a);
      y[k] = a;
    }
#pragma unroll
    for (int k = 0; k < 16; ++k)
      y[k] = fmaxf(fmaf(prm[256 + o0 + k], y[k], prm[384 + o0 + k]), 0.f);
    float m = fold_max16(y, lane);
    if (!(lane & 16))
      outp[(size_t)cs * 128 + o0 + (lane & 15)] = m;
  }
}

__global__ void finalize_kernel(const float* __restrict__ stats,
                                const float* __restrict__ g,
                                const float* __restrict__ beta,
                                float* __restrict__ pa, float* __restrict__ psh, int C)
{
  int c = threadIdx.x;
  if (c >= C) return;
  float s1 = 0.f, s2 = 0.f;
  for (int rr = 0; rr < NREP; ++rr) { s1 += stats[rr*C + c]; s2 += stats[NREP*C + rr*C + c]; }
  const float invn = 1.0f / (float)NROWS;
  float mean = s1 * invn;
  float var  = s2 * invn - mean * mean;
  float rs   = 1.0f / sqrtf(var + 1e-5f);
  float a    = g[c] * rs;
  pa[c]  = a;
  psh[c] = fmaf(-mean, a, beta[c]);
}

__global__ void zero_kernel(float* __restrict__ p, int n)
{
  int i = blockIdx.x * 256 + threadIdx.x;
  if (i < n) p[i] = 0.f;
}

// ======================== launch ========================
extern "C" void kernel_launch(void* const* d_in, const int* in_sizes, int n_in,
                              void* d_out, int out_size, void* d_ws, size_t ws_size,
                              hipStream_t stream)
{
  (void)in_sizes; (void)n_in; (void)out_size;
  const float* xyz   = (const float*)d_in[0];
  const float* feats = (const float*)d_in[1];
  const float* w0 = (const float*)d_in[2],  *b0 = (const float*)d_in[3];
  const float* g0 = (const float*)d_in[4],  *bt0 = (const float*)d_in[5];
  const float* w1 = (const float*)d_in[6],  *b1 = (const float*)d_in[7];
  const float* g1 = (const float*)d_in[8],  *bt1 = (const float*)d_in[9];
  const float* w2 = (const float*)d_in[10], *b2 = (const float*)d_in[11];
  const float* g2 = (const float*)d_in[12], *bt2 = (const float*)d_in[13];

  float* cents = (float*)d_out;                    // 8*2048*3
  float* outp  = cents + (size_t)NB * NS * 3;      // 8*2048*128

  // ws layout (R7-proven): gidx @0 (2 MiB) | stats @2MiB (64 KiB) | prm after |
  // sX/sY/sZ/sO @2MiB+512KiB (1 MiB) | zmax @4MiB | zmin @12MiB | actL @20MiB
  char* wsb = (char*)d_ws;
  int*   gidx  = (int*)wsb;
  float* stats = (float*)(wsb + (2ull << 20));
  float* prm   = stats + 16384;
  float* sX = (float*)(wsb + (2ull << 20) + (512u << 10));
  float* sY = sX + (size_t)NB * NPTS;
  float* sZ = sY + (size_t)NB * NPTS;
  unsigned* sO = (unsigned*)(sZ + (size_t)NB * NPTS);
  float* zmax  = (float*)(wsb + (4ull  << 20));
  float* zmin  = (float*)(wsb + (12ull << 20));
  unsigned short* actL = (unsigned short*)(wsb + (20ull << 20));
  const size_t need_A = (20ull << 20) + (size_t)NROWS * 64 * 2;
  const size_t need_B = (20ull << 20);

  zero_kernel<<<64, 256, 0, stream>>>(stats, 16384);
  sort_kernel<<<NB, 256, 0, stream>>>(xyz, sX, sY, sZ, sO);
  fps_kernel<<<NB, 512, 0, stream>>>(sX, sY, sZ, sO, xyz, cents);
  ballq_kernel<<<(NB*NS*64)/256, 256, 0, stream>>>(xyz, cents, gidx);

  if (ws_size >= need_A) {
    k1_kernel<<<NROWS/256, 256, 0, stream>>>(xyz, feats, cents, gidx, w0, b0, stats, actL);
    finalize_kernel<<<1, 128, 0, stream>>>(stats + 0, g0, bt0, prm + 0, prm + 64, 64);
    k2_kernel<<<NROWS/256, 256, 0, stream>>>(actL, w1, b1, prm, stats);
    finalize_kernel<<<1, 128, 0, stream>>>(stats + 4096, g1, bt1, prm + 128, prm + 192, 64);
    k3_kernel<<<NROWS/256, 256, 0, stream>>>(actL, w2, b2, prm, stats, zmax, zmin);
    finalize_kernel<<<1, 128, 0, stream>>>(stats + 8192, g2, bt2, prm + 256, prm + 384, 128);
    outfin_kernel<<<(16384*128)/256, 256, 0, stream>>>(zmax, zmin, prm, outp);
  } else if (ws_size >= need_B) {
    chain_kernel<1><<<NROWS/256, 256, 0, stream>>>(xyz, feats, cents, gidx,
        w0, b0, w1, b1, w2, b2, prm, stats, outp, zmax, zmin);
    finalize_kernel<<<1, 128, 0, stream>>>(stats + 0, g0, bt0, prm + 0, prm + 64, 64);
    chain_kernel<2><<<NROWS/256, 256, 0, stream>>>(xyz, feats, cents, gidx,
        w0, b0, w1, b1, w2, b2, prm, stats, outp, zmax, zmin);
    finalize_kernel<<<1, 128, 0, stream>>>(stats + 4096, g1, bt1, prm + 128, prm + 192, 64);
    chain_kernel<5><<<NROWS/256, 256, 0, stream>>>(xyz, feats, cents, gidx,
        w0, b0, w1, b1, w2, b2, prm, stats, outp, zmax, zmin);
    finalize_kernel<<<1, 128, 0, stream>>>(stats + 8192, g2, bt2, prm + 256, prm + 384, 128);
    outfin_kernel<<<(16384*128)/256, 256, 0, stream>>>(zmax, zmin, prm, outp);
  } else {
    chain_kernel<1><<<NROWS/256, 256, 0, stream>>>(xyz, feats, cents, gidx,
        w0, b0, w1, b1, w2, b2, prm, stats, outp, zmax, zmin);
    finalize_kernel<<<1, 128, 0, stream>>>(stats + 0, g0, bt0, prm + 0, prm + 64, 64);
    chain_kernel<2><<<NROWS/256, 256, 0, stream>>>(xyz, feats, cents, gidx,
        w0, b0, w1, b1, w2, b2, prm, stats, outp, zmax, zmin);
    finalize_kernel<<<1, 128, 0, stream>>>(stats + 4096, g1, bt1, prm + 128, prm + 192, 64);
    chain_kernel<3><<<NROWS/256, 256, 0, stream>>>(xyz, feats, cents, gidx,
        w0, b0, w1, b1, w2, b2, prm, stats, outp, zmax, zmin);
    finalize_kernel<<<1, 128, 0, stream>>>(stats + 8192, g2, bt2, prm + 256, prm + 384, 128);
    chain_kernel<4><<<NROWS/256, 256, 0, stream>>>(xyz, feats, cents, gidx,
        w0, b0, w1, b1, w2, b2, prm, stats, outp, zmax, zmin);
  }
}